// Round 9
// baseline (507.485 us; speedup 1.0000x reference)
//
#include <hip/hip_runtime.h>

#define HF  128
#define OUTF 32
#define NG  64
#define NPB 512      // nodes per bucket
#define BSHIFT 9
#define P1_VPT 16    // edges per thread in pass1
#define P2_CAP 14336 // staged csr span capacity (ints) per bucket

typedef short bf16x8 __attribute__((ext_vector_type(8)));
typedef float f32x4  __attribute__((ext_vector_type(4)));

static __device__ __forceinline__ unsigned short f2bf(float f) {
    unsigned int u = __float_as_uint(f);
    u = (u + 0x7FFFu + ((u >> 16) & 1u)) >> 16;   // RNE
    return (unsigned short)u;
}
static __device__ __forceinline__ float bf2f(unsigned short u) {
    return __uint_as_float((unsigned int)u << 16);
}
static __device__ __forceinline__ void gload_lds16(const void* g, void* l) {
    __builtin_amdgcn_global_load_lds(
        (const __attribute__((address_space(1))) unsigned int*)g,
        (__attribute__((address_space(3))) unsigned int*)l, 16, 0, 0);
}

// ---------------- init: zero sums, bucket counts, hb pad rows, dinv pad ------
__global__ void k_init(float* __restrict__ sums, int* __restrict__ gcnt,
                       unsigned short* __restrict__ hbpad, int padus,
                       float* __restrict__ dinvpad, int dpad) {
    int i = blockIdx.x * blockDim.x + threadIdx.x;
    if (i < NG * HF) sums[i] = 0.f;
    if (i < 256) gcnt[i] = 0;
    if (i < padus) hbpad[i] = 0;
    if (i < dpad) dinvpad[i] = 0.f;
}

// ---------------- bucket counts via LDS histogram ----------------
__global__ __launch_bounds__(256) void k_bcnt(const int* __restrict__ edst,
                                              int* __restrict__ gcnt, int e) {
    __shared__ int h[256];
    int t = threadIdx.x;
    h[t] = 0;
    __syncthreads();
    int base = blockIdx.x * 4096 + t * 16;
    if (base + 16 <= e) {
#pragma unroll
        for (int i = 0; i < 4; ++i) {
            int4 d = *(const int4*)&edst[base + i * 4];
            atomicAdd(&h[d.x >> BSHIFT], 1);
            atomicAdd(&h[d.y >> BSHIFT], 1);
            atomicAdd(&h[d.z >> BSHIFT], 1);
            atomicAdd(&h[d.w >> BSHIFT], 1);
        }
    } else {
        for (int i = base; i < min(base + 16, e); ++i) atomicAdd(&h[edst[i] >> BSHIFT], 1);
    }
    __syncthreads();
    if (h[t]) atomicAdd(&gcnt[t], h[t]);
}

// ---------------- scan bucket counts -> goff, bcur; rowstart[n]=E ----------
__global__ __launch_bounds__(256) void k_bscan(const int* __restrict__ gcnt,
                                               int* __restrict__ goff,
                                               int* __restrict__ bcur,
                                               int* __restrict__ rowstart, int n, int nbk) {
    __shared__ int s[256];
    int t = threadIdx.x;
    int v = (t < nbk) ? gcnt[t] : 0;
    s[t] = v;
    __syncthreads();
    for (int off = 1; off < 256; off <<= 1) {
        int u = (t >= off) ? s[t - off] : 0;
        __syncthreads();
        s[t] += u;
        __syncthreads();
    }
    if (t == 0) goff[0] = 0;
    goff[t + 1] = s[t];
    bcur[t] = s[t] - v;
    if (t == 255) rowstart[n] = s[255];
}

// ---------------- pass1: coarse bucket (dst>>9), LDS-ranked grouped writes ----
// packed entry: (dst & 511) << 20 | src   (requires n < 2^20)
__global__ __launch_bounds__(256) void k_pass1(const int* __restrict__ esrc,
                                               const int* __restrict__ edst,
                                               int* __restrict__ bcur,
                                               int* __restrict__ ebuf, int e) {
    __shared__ int hist[256];
    __shared__ int base[256];
    int t = threadIdx.x;
    int c0 = blockIdx.x * (256 * P1_VPT);
    hist[t] = 0;
    __syncthreads();
    int s[P1_VPT], d[P1_VPT], r[P1_VPT];
#pragma unroll
    for (int i = 0; i < P1_VPT; ++i) {
        int idx = c0 + t + i * 256;
        if (idx < e) {
            s[i] = esrc[idx];
            d[i] = edst[idx];
            r[i] = atomicAdd(&hist[d[i] >> BSHIFT], 1);
        }
    }
    __syncthreads();
    int cnt = hist[t];
    base[t] = (cnt > 0) ? atomicAdd(&bcur[t], cnt) : 0;
    __syncthreads();
#pragma unroll
    for (int i = 0; i < P1_VPT; ++i) {
        int idx = c0 + t + i * 256;
        if (idx < e)
            ebuf[base[d[i] >> BSHIFT] + r[i]] = ((d[i] & (NPB - 1)) << 20) | s[i];
    }
}

// ---- pass2 (fused): per-bucket degree count + scan + rowstart + dinv + scatter
__global__ __launch_bounds__(256) void k_pass2(const int* __restrict__ ebuf,
                                               const int* __restrict__ goff,
                                               int* __restrict__ rowstart,
                                               int* __restrict__ csr,
                                               float* __restrict__ dinv, int n) {
    __shared__ int ldeg[NPB];
    __shared__ int lexc[NPB];
    __shared__ int s[256];
    __shared__ int lbuf[P2_CAP];
    int b = blockIdx.x, t = threadIdx.x;
    int node0 = b << BSHIFT;
    int nn = min(NPB, n - node0);
    int bbase = goff[b];
    int span = goff[b + 1] - bbase;
    ldeg[t] = 0;
    ldeg[t + 256] = 0;
    __syncthreads();
    for (int i = t; i < span; i += 256) atomicAdd(&ldeg[ebuf[bbase + i] >> 20], 1);
    __syncthreads();
    int d0 = ldeg[2 * t], d1 = ldeg[2 * t + 1];
    s[t] = d0 + d1;
    __syncthreads();
    for (int off = 1; off < 256; off <<= 1) {
        int u = (t >= off) ? s[t - off] : 0;
        __syncthreads();
        s[t] += u;
        __syncthreads();
    }
    int exc = s[t] - (d0 + d1);
    lexc[2 * t] = exc;
    lexc[2 * t + 1] = exc + d0;
    if (2 * t < nn) {
        rowstart[node0 + 2 * t] = bbase + exc;
        dinv[node0 + 2 * t] = rsqrtf((float)d0 + 1.0f);
    }
    if (2 * t + 1 < nn) {
        rowstart[node0 + 2 * t + 1] = bbase + exc + d0;
        dinv[node0 + 2 * t + 1] = rsqrtf((float)d1 + 1.0f);
    }
    __syncthreads();
    if (span <= P2_CAP) {
        for (int i = t; i < span; i += 256) {
            int v = ebuf[bbase + i];
            int lp = atomicAdd(&lexc[v >> 20], 1);
            lbuf[lp] = v & 0xFFFFF;
        }
        __syncthreads();
        for (int i = t; i < span; i += 256) csr[bbase + i] = lbuf[i];
    } else {  // safety fallback
        for (int i = t; i < span; i += 256) {
            int v = ebuf[bbase + i];
            int lp = atomicAdd(&lexc[v >> 20], 1);
            csr[bbase + lp] = v & 0xFFFFF;
        }
    }
}

// ---------------- W prep: transpose + bf16 hi/lo split (lo pre-swizzled) ----
__global__ __launch_bounds__(256) void k_wprep(const float* __restrict__ W1,
                                               const float* __restrict__ W2,
                                               const float* __restrict__ W3,
                                               unsigned short* __restrict__ wh,
                                               unsigned short* __restrict__ wl) {
    const float* W = (blockIdx.x == 0) ? W1 : ((blockIdx.x == 1) ? W2 : W3);
    unsigned short* whb = wh + blockIdx.x * 16384;
    unsigned short* wlb = wl + blockIdx.x * 16384;
    int t = threadIdx.x;
    int c = t & 127, kh = (t >> 7) * 64;
    int sw = (c & 7) << 3;
    for (int k = kh; k < kh + 64; ++k) {
        float v = W[k * HF + c];
        unsigned short hi = f2bf(v);
        float r = v - bf2f(hi);
        whb[c * HF + k] = hi;
        wlb[c * HF + (k ^ sw)] = f2bf(r);
    }
}

// ---------------- MFMA GEMM: T = bf16((A @ W) * dinv), 128x128 tile ----------
__global__ __launch_bounds__(256) void k_gemm(const float* __restrict__ Afp,
                                              const unsigned short* __restrict__ Abf,
                                              const unsigned short* __restrict__ wthi,
                                              const unsigned short* __restrict__ wtlo,
                                              const float* __restrict__ dinv,
                                              unsigned short* __restrict__ T, int n) {
    __shared__ unsigned short As[16384];  // swizzled [row][k] bf16 (reused for C)
    __shared__ unsigned short Wl[16384];  // swizzled [col][k] bf16
    int t = threadIdx.x;
    int l = t & 63, w = t >> 6;
    int row0 = blockIdx.x * 128;
    int lm = l & 15, lg = l >> 4;

    // stage W-lo (pre-swizzled source -> linear LDS)
#pragma unroll
    for (int p = 0; p < 8; ++p)
        gload_lds16(&wtlo[(size_t)(p * 256 + t) * 8], &Wl[(size_t)(p * 256 + w * 64) * 8]);

    // stage A (swizzled image)
    if (Afp) {
#pragma unroll
        for (int p = 0; p < 8; ++p) {
            int cid = p * 256 + t;
            int row = cid >> 4, ch = cid & 15;
            int gr = row0 + row;
            float4 f0 = make_float4(0.f, 0.f, 0.f, 0.f), f1 = f0;
            if (gr < n) {
                f0 = *(const float4*)&Afp[(size_t)gr * HF + ch * 8];
                f1 = *(const float4*)&Afp[(size_t)gr * HF + ch * 8 + 4];
            }
            uint4 u;
            u.x = f2bf(f0.x) | ((unsigned)f2bf(f0.y) << 16);
            u.y = f2bf(f0.z) | ((unsigned)f2bf(f0.w) << 16);
            u.z = f2bf(f1.x) | ((unsigned)f2bf(f1.y) << 16);
            u.w = f2bf(f1.z) | ((unsigned)f2bf(f1.w) << 16);
            *(uint4*)((char*)As + row * 256 + ((ch * 16) ^ ((row & 7) << 4))) = u;
        }
    } else {
#pragma unroll
        for (int p = 0; p < 8; ++p) {
            int cid = p * 256 + t;
            int row = cid >> 4, ch = cid & 15;
            const char* src = (const char*)Abf + (size_t)(row0 + row) * 256 +
                              ((ch * 16) ^ ((row & 7) << 4));
            gload_lds16(src, (char*)As + (size_t)(p * 256 + w * 64) * 16);
        }
    }

    // W-hi fragments into registers (L2-hot global reads)
    int wr = (w >> 1) * 64, wc = (w & 1) * 64;
    bf16x8 bh[4][4];
#pragma unroll
    for (int ni = 0; ni < 4; ++ni)
#pragma unroll
        for (int kk = 0; kk < 4; ++kk)
            bh[ni][kk] = *(const bf16x8*)&wthi[(size_t)(wc + ni * 16 + lm) * HF + kk * 32 + lg * 8];

    __syncthreads();

    f32x4 acc[4][4];
#pragma unroll
    for (int mi = 0; mi < 4; ++mi)
#pragma unroll
        for (int ni = 0; ni < 4; ++ni) {
            f32x4 z = {0.f, 0.f, 0.f, 0.f};
            acc[mi][ni] = z;
        }

    int swz = (l & 7) << 4;
#pragma unroll
    for (int kk = 0; kk < 4; ++kk) {
        int kb = (kk * 64 + lg * 16) ^ swz;
        bf16x8 a[4], bl[4];
#pragma unroll
        for (int mi = 0; mi < 4; ++mi)
            a[mi] = *(bf16x8*)((char*)As + (wr + mi * 16 + lm) * 256 + kb);
#pragma unroll
        for (int ni = 0; ni < 4; ++ni)
            bl[ni] = *(bf16x8*)((char*)Wl + (wc + ni * 16 + lm) * 256 + kb);
#pragma unroll
        for (int mi = 0; mi < 4; ++mi)
#pragma unroll
            for (int ni = 0; ni < 4; ++ni) {
                acc[mi][ni] = __builtin_amdgcn_mfma_f32_16x16x32_bf16(a[mi], bh[ni][kk], acc[mi][ni], 0, 0, 0);
                acc[mi][ni] = __builtin_amdgcn_mfma_f32_16x16x32_bf16(a[mi], bl[ni], acc[mi][ni], 0, 0, 0);
            }
    }

    // epilogue: scale by dinv, bf16 into LDS (linear), coalesced uint4 store
    __syncthreads();   // everyone done reading As/Wl
#pragma unroll
    for (int mi = 0; mi < 4; ++mi) {
        int rb = wr + mi * 16 + lg * 4;
        f32x4 dv = *(const f32x4*)&dinv[row0 + rb];
#pragma unroll
        for (int ni = 0; ni < 4; ++ni) {
            int col = wc + ni * 16 + lm;
#pragma unroll
            for (int j = 0; j < 4; ++j)
                As[(rb + j) * HF + col] = f2bf(acc[mi][ni][j] * dv[j]);
        }
    }
    __syncthreads();
#pragma unroll
    for (int p = 0; p < 8; ++p) {
        int c = p * 256 + t;   // 16B chunk id, 0..2047
        *(uint4*)((char*)(T + (size_t)row0 * HF) + (size_t)c * 16) =
            *(const uint4*)((const char*)As + (size_t)c * 16);
    }
}

// ------- pull-aggregate: 4 nodes/wave, 16 lanes/node, unroll 4 --------------
// sums==nullptr: relu + bf16 store to outb (hidden layers)
// sums!=nullptr: layer 3 fused with mean-pool (LDS group acc -> global atomic)
__global__ __launch_bounds__(256) void k_pull(const unsigned short* __restrict__ ts,
                                              const int* __restrict__ csr,
                                              const int* __restrict__ rowstart,
                                              const float* __restrict__ dinv,
                                              const float* __restrict__ bias,
                                              unsigned short* __restrict__ outb,
                                              const int* __restrict__ batch,
                                              float* __restrict__ sums, int n) {
    __shared__ float lacc[16 * HF];   // 16 group slots (block spans <=16 groups)
    int t = threadIdx.x;
    int tid = blockIdx.x * 256 + t;
    int sg = tid >> 4;
    int sl = tid & 15;
    bool act = sg < n;
    bool pool = (sums != nullptr);
    if (pool) {
        for (int i = t; i < 16 * HF; i += 256) lacc[i] = 0.f;
        __syncthreads();
    }
    int f0 = sl * 8;
    float a0 = 0.f, a1 = 0.f, a2 = 0.f, a3 = 0.f, a4 = 0.f, a5 = 0.f, a6 = 0.f, a7 = 0.f;
    float o0 = 0.f, o1 = 0.f, o2 = 0.f, o3 = 0.f, o4 = 0.f, o5 = 0.f, o6 = 0.f, o7 = 0.f;
    if (act) {
        uint4 sv = *(const uint4*)&ts[(size_t)sg * HF + f0];
        a0 = __uint_as_float(sv.x << 16); a1 = __uint_as_float(sv.x & 0xFFFF0000u);
        a2 = __uint_as_float(sv.y << 16); a3 = __uint_as_float(sv.y & 0xFFFF0000u);
        a4 = __uint_as_float(sv.z << 16); a5 = __uint_as_float(sv.z & 0xFFFF0000u);
        a6 = __uint_as_float(sv.w << 16); a7 = __uint_as_float(sv.w & 0xFFFF0000u);
        int e  = rowstart[sg];
        int e1 = rowstart[sg + 1];
#define ACC8(v) \
        a0 += __uint_as_float(v.x << 16); a1 += __uint_as_float(v.x & 0xFFFF0000u); \
        a2 += __uint_as_float(v.y << 16); a3 += __uint_as_float(v.y & 0xFFFF0000u); \
        a4 += __uint_as_float(v.z << 16); a5 += __uint_as_float(v.z & 0xFFFF0000u); \
        a6 += __uint_as_float(v.w << 16); a7 += __uint_as_float(v.w & 0xFFFF0000u);
        for (; e + 4 <= e1; e += 4) {
            int s0 = csr[e], s1 = csr[e + 1], s2 = csr[e + 2], s3 = csr[e + 3];
            uint4 v0 = *(const uint4*)&ts[(size_t)s0 * HF + f0];
            uint4 v1 = *(const uint4*)&ts[(size_t)s1 * HF + f0];
            uint4 v2 = *(const uint4*)&ts[(size_t)s2 * HF + f0];
            uint4 v3 = *(const uint4*)&ts[(size_t)s3 * HF + f0];
            ACC8(v0) ACC8(v1) ACC8(v2) ACC8(v3)
        }
        for (; e < e1; ++e) {
            int sx = csr[e];
            uint4 v = *(const uint4*)&ts[(size_t)sx * HF + f0];
            ACC8(v)
        }
#undef ACC8
        float d = dinv[sg];
        float4 blv = *(const float4*)&bias[f0];
        float4 bhv = *(const float4*)&bias[f0 + 4];
        o0 = a0 * d + blv.x; o1 = a1 * d + blv.y; o2 = a2 * d + blv.z; o3 = a3 * d + blv.w;
        o4 = a4 * d + bhv.x; o5 = a5 * d + bhv.y; o6 = a6 * d + bhv.z; o7 = a7 * d + bhv.w;
    }
    if (!pool) {
        if (act) {
            o0 = fmaxf(o0, 0.f); o1 = fmaxf(o1, 0.f); o2 = fmaxf(o2, 0.f); o3 = fmaxf(o3, 0.f);
            o4 = fmaxf(o4, 0.f); o5 = fmaxf(o5, 0.f); o6 = fmaxf(o6, 0.f); o7 = fmaxf(o7, 0.f);
            uint4 u;
            u.x = f2bf(o0) | ((unsigned)f2bf(o1) << 16);
            u.y = f2bf(o2) | ((unsigned)f2bf(o3) << 16);
            u.z = f2bf(o4) | ((unsigned)f2bf(o5) << 16);
            u.w = f2bf(o6) | ((unsigned)f2bf(o7) << 16);
            *(uint4*)&outb[(size_t)sg * HF + f0] = u;
        }
        return;
    }
    // fused mean-pool accumulate (no relu on layer 3)
    int sg0 = (blockIdx.x * 256) >> 4;
    int g0 = batch[min(sg0, n - 1)];
    if (act) {
        int slot = batch[sg] - g0;          // batch sorted => 0..15
        float* lp = &lacc[slot * HF + f0];
        atomicAdd(lp + 0, o0); atomicAdd(lp + 1, o1);
        atomicAdd(lp + 2, o2); atomicAdd(lp + 3, o3);
        atomicAdd(lp + 4, o4); atomicAdd(lp + 5, o5);
        atomicAdd(lp + 6, o6); atomicAdd(lp + 7, o7);
    }
    __syncthreads();
    int nslots = batch[min(sg0 + 15, n - 1)] - g0 + 1;
    for (int i = t; i < nslots * HF; i += 256)
        atomicAdd(&sums[(g0 + (i >> 7)) * HF + (i & 127)], lacc[i]);
}

// ---------------- head MLP (counts fused) ----------------
__global__ __launch_bounds__(512) void k_head(const float* __restrict__ sums,
                                              const int* __restrict__ batch, int n,
                                              const float* __restrict__ Wo1,
                                              const float* __restrict__ bo1,
                                              const float* __restrict__ Wo2,
                                              const float* __restrict__ bo2,
                                              float* __restrict__ outp) {
    __shared__ float cnt[NG];
    __shared__ float P[NG * 128];
    __shared__ float Z[NG * 64];
    int t = threadIdx.x;
    if (t < NG) {
        int g = t;
        int lo = 0, hi = n;
        while (lo < hi) { int mid = (lo + hi) >> 1; if (batch[mid] < g) lo = mid + 1; else hi = mid; }
        int a = lo;
        lo = 0; hi = n;
        int key = g + 1;
        while (lo < hi) { int mid = (lo + hi) >> 1; if (batch[mid] < key) lo = mid + 1; else hi = mid; }
        cnt[g] = (float)(lo - a);
    }
    __syncthreads();
    for (int i = t; i < NG * 128; i += 512) {
        int g = i >> 7;
        P[i] = sums[i] / fmaxf(cnt[g], 1.f);
    }
    __syncthreads();
    for (int i = t; i < NG * 64; i += 512) {
        int g = i >> 6, c = i & 63;
        float s = bo1[c];
        for (int k = 0; k < 128; ++k) s += P[g * 128 + k] * Wo1[k * 64 + c];
        Z[i] = fmaxf(s, 0.f);
    }
    __syncthreads();
    for (int i = t; i < NG * OUTF; i += 512) {
        int g = i >> 5, c = i & 31;
        float s = bo2[c];
        for (int k = 0; k < 64; ++k) s += Z[g * 64 + k] * Wo2[k * 32 + c];
        outp[i] = s;
    }
}

extern "C" void kernel_launch(void* const* d_in, const int* in_sizes, int n_in,
                              void* d_out, int out_size, void* d_ws, size_t ws_size,
                              hipStream_t stream) {
    const float* x    = (const float*)d_in[0];
    const int*   ei   = (const int*)d_in[1];
    const int*   batch= (const int*)d_in[2];
    const float* W1   = (const float*)d_in[3];
    const float* b1   = (const float*)d_in[4];
    const float* W2   = (const float*)d_in[5];
    const float* b2   = (const float*)d_in[6];
    const float* W3   = (const float*)d_in[7];
    const float* b3   = (const float*)d_in[8];
    const float* Wo1  = (const float*)d_in[9];
    const float* bo1  = (const float*)d_in[10];
    const float* Wo2  = (const float*)d_in[11];
    const float* bo2  = (const float*)d_in[12];

    int n = in_sizes[0] / HF;
    int e = in_sizes[1] / 2;
    const int* esrc = ei;
    const int* edst = ei + e;
    int npad = ((n + 127) / 128) * 128;

    char* ws = (char*)d_ws;
    auto align = [](size_t v) { return (v + 255) & ~(size_t)255; };
    size_t off = 0;
    int*   rowstart = (int*)(ws + off); off = align(off + sizeof(int) * (n + 1));
    int*   csr      = (int*)(ws + off); off = align(off + sizeof(int) * e);
    int*   ebuf     = (int*)(ws + off); off = align(off + sizeof(int) * (size_t)e);
    float* dinv     = (float*)(ws + off); off = align(off + sizeof(float) * npad);
    unsigned short* tbuf = (unsigned short*)(ws + off); off = align(off + sizeof(short) * (size_t)npad * HF);
    unsigned short* hb   = (unsigned short*)(ws + off); off = align(off + sizeof(short) * (size_t)npad * HF);
    float* sums     = (float*)(ws + off); off = align(off + sizeof(float) * NG * HF);
    int*   gcnt     = (int*)(ws + off); off = align(off + sizeof(int) * 256);
    int*   goff     = (int*)(ws + off); off = align(off + sizeof(int) * 257);
    int*   bcur     = (int*)(ws + off); off = align(off + sizeof(int) * 256);
    unsigned short* wh = (unsigned short*)(ws + off); off = align(off + sizeof(short) * 3 * 16384);
    unsigned short* wl = (unsigned short*)(ws + off); off = align(off + sizeof(short) * 3 * 16384);

    int nbk = (n + NPB - 1) >> BSHIFT;
    int padus = (npad - n) * HF;
    int dpad = npad - n;

    k_init<<<64, 256, 0, stream>>>(sums, gcnt, hb + (size_t)n * HF, padus, dinv + n, dpad);
    k_bcnt<<<(e + 4095) / 4096, 256, 0, stream>>>(edst, gcnt, e);
    k_bscan<<<1, 256, 0, stream>>>(gcnt, goff, bcur, rowstart, n, nbk);
    k_pass1<<<(e + 256 * P1_VPT - 1) / (256 * P1_VPT), 256, 0, stream>>>(esrc, edst, bcur, ebuf, e);
    k_pass2<<<nbk, 256, 0, stream>>>(ebuf, goff, rowstart, csr, dinv, n);
    k_wprep<<<3, 256, 0, stream>>>(W1, W2, W3, wh, wl);

    int gemm_grid = npad / 128;
    int pull_grid = (int)(((size_t)n * 16 + 255) / 256);

    k_gemm<<<gemm_grid, 256, 0, stream>>>(x, hb, wh, wl, dinv, tbuf, n);
    k_pull<<<pull_grid, 256, 0, stream>>>(tbuf, csr, rowstart, dinv, b1, hb, batch, nullptr, n);
    k_gemm<<<gemm_grid, 256, 0, stream>>>(nullptr, hb, wh + 16384, wl + 16384, dinv, tbuf, n);
    k_pull<<<pull_grid, 256, 0, stream>>>(tbuf, csr, rowstart, dinv, b2, hb, batch, nullptr, n);
    k_gemm<<<gemm_grid, 256, 0, stream>>>(nullptr, hb, wh + 32768, wl + 32768, dinv, tbuf, n);
    k_pull<<<pull_grid, 256, 0, stream>>>(tbuf, csr, rowstart, dinv, b3, nullptr, batch, sums, n);

    k_head<<<1, 512, 0, stream>>>(sums, batch, n, Wo1, bo1, Wo2, bo2, (float*)d_out);
}

// Round 10
// 468.148 us; speedup vs baseline: 1.0840x; 1.0840x over previous
//
#include <hip/hip_runtime.h>

#define HF  128
#define OUTF 32
#define NG  64
#define NPB 512      // nodes per bucket
#define BSHIFT 9
#define P1_VPT 16    // edges per thread in pass1
#define P2_CAP 14336 // staged csr span capacity (ints) per bucket

typedef short bf16x8 __attribute__((ext_vector_type(8)));
typedef float f32x4  __attribute__((ext_vector_type(4)));

static __device__ __forceinline__ unsigned short f2bf(float f) {
    unsigned int u = __float_as_uint(f);
    u = (u + 0x7FFFu + ((u >> 16) & 1u)) >> 16;   // RNE
    return (unsigned short)u;
}
static __device__ __forceinline__ float bf2f(unsigned short u) {
    return __uint_as_float((unsigned int)u << 16);
}
static __device__ __forceinline__ void gload_lds16(const void* g, void* l) {
    __builtin_amdgcn_global_load_lds(
        (const __attribute__((address_space(1))) unsigned int*)g,
        (__attribute__((address_space(3))) unsigned int*)l, 16, 0, 0);
}

// ---------------- init: zero sums, bucket counts, hb pad rows, dinv pad ------
__global__ void k_init(float* __restrict__ sums, int* __restrict__ gcnt,
                       unsigned short* __restrict__ hbpad, int padus,
                       float* __restrict__ dinvpad, int dpad) {
    int i = blockIdx.x * blockDim.x + threadIdx.x;
    if (i < NG * HF) sums[i] = 0.f;
    if (i < 256) gcnt[i] = 0;
    if (i < padus) hbpad[i] = 0;
    if (i < dpad) dinvpad[i] = 0.f;
}

// ---------------- bucket counts via LDS histogram ----------------
__global__ __launch_bounds__(256) void k_bcnt(const int* __restrict__ edst,
                                              int* __restrict__ gcnt, int e) {
    __shared__ int h[256];
    int t = threadIdx.x;
    h[t] = 0;
    __syncthreads();
    int base = blockIdx.x * 4096 + t * 16;
    if (base + 16 <= e) {
#pragma unroll
        for (int i = 0; i < 4; ++i) {
            int4 d = *(const int4*)&edst[base + i * 4];
            atomicAdd(&h[d.x >> BSHIFT], 1);
            atomicAdd(&h[d.y >> BSHIFT], 1);
            atomicAdd(&h[d.z >> BSHIFT], 1);
            atomicAdd(&h[d.w >> BSHIFT], 1);
        }
    } else {
        for (int i = base; i < min(base + 16, e); ++i) atomicAdd(&h[edst[i] >> BSHIFT], 1);
    }
    __syncthreads();
    if (h[t]) atomicAdd(&gcnt[t], h[t]);
}

// ---------------- scan bucket counts -> goff, bcur; rowstart[n]=E ----------
__global__ __launch_bounds__(256) void k_bscan(const int* __restrict__ gcnt,
                                               int* __restrict__ goff,
                                               int* __restrict__ bcur,
                                               int* __restrict__ rowstart, int n, int nbk) {
    __shared__ int s[256];
    int t = threadIdx.x;
    int v = (t < nbk) ? gcnt[t] : 0;
    s[t] = v;
    __syncthreads();
    for (int off = 1; off < 256; off <<= 1) {
        int u = (t >= off) ? s[t - off] : 0;
        __syncthreads();
        s[t] += u;
        __syncthreads();
    }
    if (t == 0) goff[0] = 0;
    goff[t + 1] = s[t];
    bcur[t] = s[t] - v;
    if (t == 255) rowstart[n] = s[255];
}

// ---------------- pass1: coarse bucket (dst>>9), LDS-ranked grouped writes ----
// packed entry: (dst & 511) << 20 | src   (requires n < 2^20)
__global__ __launch_bounds__(256) void k_pass1(const int* __restrict__ esrc,
                                               const int* __restrict__ edst,
                                               int* __restrict__ bcur,
                                               int* __restrict__ ebuf, int e) {
    __shared__ int hist[256];
    __shared__ int base[256];
    int t = threadIdx.x;
    int c0 = blockIdx.x * (256 * P1_VPT);
    hist[t] = 0;
    __syncthreads();
    int s[P1_VPT], d[P1_VPT], r[P1_VPT];
#pragma unroll
    for (int i = 0; i < P1_VPT; ++i) {
        int idx = c0 + t + i * 256;
        if (idx < e) {
            s[i] = esrc[idx];
            d[i] = edst[idx];
            r[i] = atomicAdd(&hist[d[i] >> BSHIFT], 1);
        }
    }
    __syncthreads();
    int cnt = hist[t];
    base[t] = (cnt > 0) ? atomicAdd(&bcur[t], cnt) : 0;
    __syncthreads();
#pragma unroll
    for (int i = 0; i < P1_VPT; ++i) {
        int idx = c0 + t + i * 256;
        if (idx < e)
            ebuf[base[d[i] >> BSHIFT] + r[i]] = ((d[i] & (NPB - 1)) << 20) | s[i];
    }
}

// ---- pass2 (fused): per-bucket degree count + scan + rowstart + dinv + scatter
__global__ __launch_bounds__(256) void k_pass2(const int* __restrict__ ebuf,
                                               const int* __restrict__ goff,
                                               int* __restrict__ rowstart,
                                               int* __restrict__ csr,
                                               float* __restrict__ dinv, int n) {
    __shared__ int ldeg[NPB];
    __shared__ int lexc[NPB];
    __shared__ int s[256];
    __shared__ int lbuf[P2_CAP];
    int b = blockIdx.x, t = threadIdx.x;
    int node0 = b << BSHIFT;
    int nn = min(NPB, n - node0);
    int bbase = goff[b];
    int span = goff[b + 1] - bbase;
    ldeg[t] = 0;
    ldeg[t + 256] = 0;
    __syncthreads();
    for (int i = t; i < span; i += 256) atomicAdd(&ldeg[ebuf[bbase + i] >> 20], 1);
    __syncthreads();
    int d0 = ldeg[2 * t], d1 = ldeg[2 * t + 1];
    s[t] = d0 + d1;
    __syncthreads();
    for (int off = 1; off < 256; off <<= 1) {
        int u = (t >= off) ? s[t - off] : 0;
        __syncthreads();
        s[t] += u;
        __syncthreads();
    }
    int exc = s[t] - (d0 + d1);
    lexc[2 * t] = exc;
    lexc[2 * t + 1] = exc + d0;
    if (2 * t < nn) {
        rowstart[node0 + 2 * t] = bbase + exc;
        dinv[node0 + 2 * t] = rsqrtf((float)d0 + 1.0f);
    }
    if (2 * t + 1 < nn) {
        rowstart[node0 + 2 * t + 1] = bbase + exc + d0;
        dinv[node0 + 2 * t + 1] = rsqrtf((float)d1 + 1.0f);
    }
    __syncthreads();
    if (span <= P2_CAP) {
        for (int i = t; i < span; i += 256) {
            int v = ebuf[bbase + i];
            int lp = atomicAdd(&lexc[v >> 20], 1);
            lbuf[lp] = v & 0xFFFFF;
        }
        __syncthreads();
        for (int i = t; i < span; i += 256) csr[bbase + i] = lbuf[i];
    } else {  // safety fallback
        for (int i = t; i < span; i += 256) {
            int v = ebuf[bbase + i];
            int lp = atomicAdd(&lexc[v >> 20], 1);
            csr[bbase + lp] = v & 0xFFFFF;
        }
    }
}

// ---------------- W prep: transpose + bf16 hi/lo split (lo pre-swizzled) ----
__global__ __launch_bounds__(256) void k_wprep(const float* __restrict__ W1,
                                               const float* __restrict__ W2,
                                               const float* __restrict__ W3,
                                               unsigned short* __restrict__ wh,
                                               unsigned short* __restrict__ wl) {
    const float* W = (blockIdx.x == 0) ? W1 : ((blockIdx.x == 1) ? W2 : W3);
    unsigned short* whb = wh + blockIdx.x * 16384;
    unsigned short* wlb = wl + blockIdx.x * 16384;
    int t = threadIdx.x;
    int c = t & 127, kh = (t >> 7) * 64;
    int sw = (c & 7) << 3;
    for (int k = kh; k < kh + 64; ++k) {
        float v = W[k * HF + c];
        unsigned short hi = f2bf(v);
        float r = v - bf2f(hi);
        whb[c * HF + k] = hi;
        wlb[c * HF + (k ^ sw)] = f2bf(r);
    }
}

// ---------------- MFMA GEMM: T = bf16((A @ W) * dinv), 128x128 tile ----------
__global__ __launch_bounds__(256) void k_gemm(const float* __restrict__ Afp,
                                              const unsigned short* __restrict__ Abf,
                                              const unsigned short* __restrict__ wthi,
                                              const unsigned short* __restrict__ wtlo,
                                              const float* __restrict__ dinv,
                                              unsigned short* __restrict__ T, int n) {
    __shared__ unsigned short As[16384];  // swizzled [row][k] bf16 (reused for C)
    __shared__ unsigned short Wl[16384];  // swizzled [col][k] bf16
    int t = threadIdx.x;
    int l = t & 63, w = t >> 6;
    int row0 = blockIdx.x * 128;
    int lm = l & 15, lg = l >> 4;

    // stage W-lo (pre-swizzled source -> linear LDS)
#pragma unroll
    for (int p = 0; p < 8; ++p)
        gload_lds16(&wtlo[(size_t)(p * 256 + t) * 8], &Wl[(size_t)(p * 256 + w * 64) * 8]);

    // stage A (swizzled image)
    if (Afp) {
#pragma unroll
        for (int p = 0; p < 8; ++p) {
            int cid = p * 256 + t;
            int row = cid >> 4, ch = cid & 15;
            int gr = row0 + row;
            float4 f0 = make_float4(0.f, 0.f, 0.f, 0.f), f1 = f0;
            if (gr < n) {
                f0 = *(const float4*)&Afp[(size_t)gr * HF + ch * 8];
                f1 = *(const float4*)&Afp[(size_t)gr * HF + ch * 8 + 4];
            }
            uint4 u;
            u.x = f2bf(f0.x) | ((unsigned)f2bf(f0.y) << 16);
            u.y = f2bf(f0.z) | ((unsigned)f2bf(f0.w) << 16);
            u.z = f2bf(f1.x) | ((unsigned)f2bf(f1.y) << 16);
            u.w = f2bf(f1.z) | ((unsigned)f2bf(f1.w) << 16);
            *(uint4*)((char*)As + row * 256 + ((ch * 16) ^ ((row & 7) << 4))) = u;
        }
    } else {
#pragma unroll
        for (int p = 0; p < 8; ++p) {
            int cid = p * 256 + t;
            int row = cid >> 4, ch = cid & 15;
            const char* src = (const char*)Abf + (size_t)(row0 + row) * 256 +
                              ((ch * 16) ^ ((row & 7) << 4));
            gload_lds16(src, (char*)As + (size_t)(p * 256 + w * 64) * 16);
        }
    }

    // W-hi fragments into registers (L2-hot global reads)
    int wr = (w >> 1) * 64, wc = (w & 1) * 64;
    bf16x8 bh[4][4];
#pragma unroll
    for (int ni = 0; ni < 4; ++ni)
#pragma unroll
        for (int kk = 0; kk < 4; ++kk)
            bh[ni][kk] = *(const bf16x8*)&wthi[(size_t)(wc + ni * 16 + lm) * HF + kk * 32 + lg * 8];

    __syncthreads();

    f32x4 acc[4][4];
#pragma unroll
    for (int mi = 0; mi < 4; ++mi)
#pragma unroll
        for (int ni = 0; ni < 4; ++ni) {
            f32x4 z = {0.f, 0.f, 0.f, 0.f};
            acc[mi][ni] = z;
        }

    int swz = (l & 7) << 4;
#pragma unroll
    for (int kk = 0; kk < 4; ++kk) {
        int kb = (kk * 64 + lg * 16) ^ swz;
        bf16x8 a[4], bl[4];
#pragma unroll
        for (int mi = 0; mi < 4; ++mi)
            a[mi] = *(bf16x8*)((char*)As + (wr + mi * 16 + lm) * 256 + kb);
#pragma unroll
        for (int ni = 0; ni < 4; ++ni)
            bl[ni] = *(bf16x8*)((char*)Wl + (wc + ni * 16 + lm) * 256 + kb);
#pragma unroll
        for (int mi = 0; mi < 4; ++mi)
#pragma unroll
            for (int ni = 0; ni < 4; ++ni) {
                acc[mi][ni] = __builtin_amdgcn_mfma_f32_16x16x32_bf16(a[mi], bh[ni][kk], acc[mi][ni], 0, 0, 0);
                acc[mi][ni] = __builtin_amdgcn_mfma_f32_16x16x32_bf16(a[mi], bl[ni], acc[mi][ni], 0, 0, 0);
            }
    }

    // epilogue: scale by dinv, bf16 into LDS (linear), coalesced uint4 store
    __syncthreads();   // everyone done reading As/Wl
#pragma unroll
    for (int mi = 0; mi < 4; ++mi) {
        int rb = wr + mi * 16 + lg * 4;
        f32x4 dv = *(const f32x4*)&dinv[row0 + rb];
#pragma unroll
        for (int ni = 0; ni < 4; ++ni) {
            int col = wc + ni * 16 + lm;
#pragma unroll
            for (int j = 0; j < 4; ++j)
                As[(rb + j) * HF + col] = f2bf(acc[mi][ni][j] * dv[j]);
        }
    }
    __syncthreads();
#pragma unroll
    for (int p = 0; p < 8; ++p) {
        int c = p * 256 + t;   // 16B chunk id, 0..2047
        *(uint4*)((char*)(T + (size_t)row0 * HF) + (size_t)c * 16) =
            *(const uint4*)((const char*)As + (size_t)c * 16);
    }
}

// ------- pull-aggregate: 4 nodes/wave, 16 lanes/node, unroll 4, bf16 out ----
// exact round-5 loop shape (no LDS, early return) — measured 65 us
__global__ __launch_bounds__(256) void k_pull(const unsigned short* __restrict__ ts,
                                              const int* __restrict__ csr,
                                              const int* __restrict__ rowstart,
                                              const float* __restrict__ dinv,
                                              const float* __restrict__ bias,
                                              unsigned short* __restrict__ outb,
                                              int n, int do_relu) {
    int tid = blockIdx.x * blockDim.x + threadIdx.x;
    int sg = tid >> 4;        // node id (one 16-lane subgroup per node)
    int sl = tid & 15;        // sublane: owns features sl*8 .. sl*8+7
    if (sg >= n) return;
    int f0 = sl * 8;

    uint4 sv = *(const uint4*)&ts[(size_t)sg * HF + f0];   // self term
    float a0 = __uint_as_float(sv.x << 16), a1 = __uint_as_float(sv.x & 0xFFFF0000u);
    float a2 = __uint_as_float(sv.y << 16), a3 = __uint_as_float(sv.y & 0xFFFF0000u);
    float a4 = __uint_as_float(sv.z << 16), a5 = __uint_as_float(sv.z & 0xFFFF0000u);
    float a6 = __uint_as_float(sv.w << 16), a7 = __uint_as_float(sv.w & 0xFFFF0000u);

    int e  = rowstart[sg];
    int e1 = rowstart[sg + 1];
#define ACC8(v) \
    a0 += __uint_as_float(v.x << 16); a1 += __uint_as_float(v.x & 0xFFFF0000u); \
    a2 += __uint_as_float(v.y << 16); a3 += __uint_as_float(v.y & 0xFFFF0000u); \
    a4 += __uint_as_float(v.z << 16); a5 += __uint_as_float(v.z & 0xFFFF0000u); \
    a6 += __uint_as_float(v.w << 16); a7 += __uint_as_float(v.w & 0xFFFF0000u);
    for (; e + 4 <= e1; e += 4) {
        int s0 = csr[e], s1 = csr[e + 1], s2 = csr[e + 2], s3 = csr[e + 3];
        uint4 v0 = *(const uint4*)&ts[(size_t)s0 * HF + f0];
        uint4 v1 = *(const uint4*)&ts[(size_t)s1 * HF + f0];
        uint4 v2 = *(const uint4*)&ts[(size_t)s2 * HF + f0];
        uint4 v3 = *(const uint4*)&ts[(size_t)s3 * HF + f0];
        ACC8(v0) ACC8(v1) ACC8(v2) ACC8(v3)
    }
    for (; e < e1; ++e) {
        int sx = csr[e];
        uint4 v = *(const uint4*)&ts[(size_t)sx * HF + f0];
        ACC8(v)
    }
#undef ACC8
    float d = dinv[sg];
    float4 blv = *(const float4*)&bias[f0];
    float4 bhv = *(const float4*)&bias[f0 + 4];
    float o0 = a0 * d + blv.x, o1 = a1 * d + blv.y, o2 = a2 * d + blv.z, o3 = a3 * d + blv.w;
    float o4 = a4 * d + bhv.x, o5 = a5 * d + bhv.y, o6 = a6 * d + bhv.z, o7 = a7 * d + bhv.w;
    if (do_relu) {
        o0 = fmaxf(o0, 0.f); o1 = fmaxf(o1, 0.f); o2 = fmaxf(o2, 0.f); o3 = fmaxf(o3, 0.f);
        o4 = fmaxf(o4, 0.f); o5 = fmaxf(o5, 0.f); o6 = fmaxf(o6, 0.f); o7 = fmaxf(o7, 0.f);
    }
    uint4 u;
    u.x = f2bf(o0) | ((unsigned)f2bf(o1) << 16);
    u.y = f2bf(o2) | ((unsigned)f2bf(o3) << 16);
    u.z = f2bf(o4) | ((unsigned)f2bf(o5) << 16);
    u.w = f2bf(o6) | ((unsigned)f2bf(o7) << 16);
    *(uint4*)&outb[(size_t)sg * HF + f0] = u;
}

// ---------------- mean-pool (bf16 input, run-length + atomics) --------------
__global__ __launch_bounds__(128) void k_pool(const unsigned short* __restrict__ h,
                                              const int* __restrict__ batch,
                                              float* __restrict__ sums, int n) {
    int f = threadIdx.x;
    int n0 = blockIdx.x * 64;
    int n1 = min(n0 + 64, n);
    float run = 0.f;
    int cur = batch[n0];
    for (int i = n0; i < n1; ++i) {
        int g = batch[i];
        if (g != cur) {
            atomicAdd(&sums[cur * HF + f], run);
            run = 0.f;
            cur = g;
        }
        run += bf2f(h[(size_t)i * HF + f]);
    }
    atomicAdd(&sums[cur * HF + f], run);
}

// ---------------- head MLP (counts fused) ----------------
__global__ __launch_bounds__(512) void k_head(const float* __restrict__ sums,
                                              const int* __restrict__ batch, int n,
                                              const float* __restrict__ Wo1,
                                              const float* __restrict__ bo1,
                                              const float* __restrict__ Wo2,
                                              const float* __restrict__ bo2,
                                              float* __restrict__ outp) {
    __shared__ float cnt[NG];
    __shared__ float P[NG * 128];
    __shared__ float Z[NG * 64];
    int t = threadIdx.x;
    if (t < NG) {
        int g = t;
        int lo = 0, hi = n;
        while (lo < hi) { int mid = (lo + hi) >> 1; if (batch[mid] < g) lo = mid + 1; else hi = mid; }
        int a = lo;
        lo = 0; hi = n;
        int key = g + 1;
        while (lo < hi) { int mid = (lo + hi) >> 1; if (batch[mid] < key) lo = mid + 1; else hi = mid; }
        cnt[g] = (float)(lo - a);
    }
    __syncthreads();
    for (int i = t; i < NG * 128; i += 512) {
        int g = i >> 7;
        P[i] = sums[i] / fmaxf(cnt[g], 1.f);
    }
    __syncthreads();
    for (int i = t; i < NG * 64; i += 512) {
        int g = i >> 6, c = i & 63;
        float s = bo1[c];
        for (int k = 0; k < 128; ++k) s += P[g * 128 + k] * Wo1[k * 64 + c];
        Z[i] = fmaxf(s, 0.f);
    }
    __syncthreads();
    for (int i = t; i < NG * OUTF; i += 512) {
        int g = i >> 5, c = i & 31;
        float s = bo2[c];
        for (int k = 0; k < 64; ++k) s += Z[g * 64 + k] * Wo2[k * 32 + c];
        outp[i] = s;
    }
}

extern "C" void kernel_launch(void* const* d_in, const int* in_sizes, int n_in,
                              void* d_out, int out_size, void* d_ws, size_t ws_size,
                              hipStream_t stream) {
    const float* x    = (const float*)d_in[0];
    const int*   ei   = (const int*)d_in[1];
    const int*   batch= (const int*)d_in[2];
    const float* W1   = (const float*)d_in[3];
    const float* b1   = (const float*)d_in[4];
    const float* W2   = (const float*)d_in[5];
    const float* b2   = (const float*)d_in[6];
    const float* W3   = (const float*)d_in[7];
    const float* b3   = (const float*)d_in[8];
    const float* Wo1  = (const float*)d_in[9];
    const float* bo1  = (const float*)d_in[10];
    const float* Wo2  = (const float*)d_in[11];
    const float* bo2  = (const float*)d_in[12];

    int n = in_sizes[0] / HF;
    int e = in_sizes[1] / 2;
    const int* esrc = ei;
    const int* edst = ei + e;
    int npad = ((n + 127) / 128) * 128;

    char* ws = (char*)d_ws;
    auto align = [](size_t v) { return (v + 255) & ~(size_t)255; };
    size_t off = 0;
    int*   rowstart = (int*)(ws + off); off = align(off + sizeof(int) * (n + 1));
    int*   csr      = (int*)(ws + off); off = align(off + sizeof(int) * e);
    int*   ebuf     = (int*)(ws + off); off = align(off + sizeof(int) * (size_t)e);
    float* dinv     = (float*)(ws + off); off = align(off + sizeof(float) * npad);
    unsigned short* tbuf = (unsigned short*)(ws + off); off = align(off + sizeof(short) * (size_t)npad * HF);
    unsigned short* hb   = (unsigned short*)(ws + off); off = align(off + sizeof(short) * (size_t)npad * HF);
    float* sums     = (float*)(ws + off); off = align(off + sizeof(float) * NG * HF);
    int*   gcnt     = (int*)(ws + off); off = align(off + sizeof(int) * 256);
    int*   goff     = (int*)(ws + off); off = align(off + sizeof(int) * 257);
    int*   bcur     = (int*)(ws + off); off = align(off + sizeof(int) * 256);
    unsigned short* wh = (unsigned short*)(ws + off); off = align(off + sizeof(short) * 3 * 16384);
    unsigned short* wl = (unsigned short*)(ws + off); off = align(off + sizeof(short) * 3 * 16384);

    int nbk = (n + NPB - 1) >> BSHIFT;
    int padus = (npad - n) * HF;
    int dpad = npad - n;

    k_init<<<64, 256, 0, stream>>>(sums, gcnt, hb + (size_t)n * HF, padus, dinv + n, dpad);
    k_bcnt<<<(e + 4095) / 4096, 256, 0, stream>>>(edst, gcnt, e);
    k_bscan<<<1, 256, 0, stream>>>(gcnt, goff, bcur, rowstart, n, nbk);
    k_pass1<<<(e + 256 * P1_VPT - 1) / (256 * P1_VPT), 256, 0, stream>>>(esrc, edst, bcur, ebuf, e);
    k_pass2<<<nbk, 256, 0, stream>>>(ebuf, goff, rowstart, csr, dinv, n);
    k_wprep<<<3, 256, 0, stream>>>(W1, W2, W3, wh, wl);

    int gemm_grid = npad / 128;
    int pull_grid = (int)(((size_t)n * 16 + 255) / 256);

    k_gemm<<<gemm_grid, 256, 0, stream>>>(x, hb, wh, wl, dinv, tbuf, n);
    k_pull<<<pull_grid, 256, 0, stream>>>(tbuf, csr, rowstart, dinv, b1, hb, n, 1);
    k_gemm<<<gemm_grid, 256, 0, stream>>>(nullptr, hb, wh + 16384, wl + 16384, dinv, tbuf, n);
    k_pull<<<pull_grid, 256, 0, stream>>>(tbuf, csr, rowstart, dinv, b2, hb, n, 1);
    k_gemm<<<gemm_grid, 256, 0, stream>>>(nullptr, hb, wh + 32768, wl + 32768, dinv, tbuf, n);
    k_pull<<<pull_grid, 256, 0, stream>>>(tbuf, csr, rowstart, dinv, b3, hb, n, 0);

    k_pool<<<(n + 63) / 64, 128, 0, stream>>>(hb, batch, sums, n);
    k_head<<<1, 512, 0, stream>>>(sums, batch, n, Wo1, bo1, Wo2, bo2, (float*)d_out);
}